// Round 1
// baseline (148.622 us; speedup 1.0000x reference)
//
#include <hip/hip_runtime.h>

// ConvCapsuleLayer: B=2, 48x48, IN_CAPS=8, ATOMS=16, KER=3, OUT_CAPS=16, R=3.
// One 256-thread block per pixel (N=4232). Thread t=(o=t>>4, a=(t>>2)&3, c=t&3).
// Round-12: occupancy push. Kernel is latency-bound (VALUBusy 52%, occ 34%,
// HBM 3.6%); LDS 26.6KB capped residency at 6 blocks/CU. Diet to 20.46KB ->
// 8 blocks/CU (32 waves = HW max):
//  - pose_s DROPPED (5.8KB): fused phase reads pose rows from pose_t via 16
//    scalar b32 (banks (12j+kf)%32, hf-broadcast -> conflict-free).
//  - coup_s stride 76->72 (reads: bases (8o+8p)%32 distinct per-o, free;
//    writes: hf 2-way, free).
//  - g_s skew o*4 -> o*8: producer stores now exactly 2-way (was 4-way at
//    banks 12..15); consumer b128 reads stay 2-way (hf collision).
//  - r=0 coupling init folded into the load loop (-1 barrier, -1 phase).
//  - __launch_bounds__(256,8) to pin regalloc at <=64 VGPR (8 blocks/CU).

#define IN_CAPS 8
#define OUT_CAPS 16
#define KK 9
#define KKIN 72
#define BATCH 2
#define H_IN 48
#define W_IN 48
#define HO 46
#define WO 46
#define CIN 136
#define NPIX (BATCH*HO*WO)   // 4232

typedef float v2f __attribute__((ext_vector_type(2)));
typedef float v4f __attribute__((ext_vector_type(4)));

__device__ __forceinline__ v2f lo2(v4f v) { return __builtin_shufflevector(v, v, 0, 1); }
__device__ __forceinline__ v2f hi2(v4f v) { return __builtin_shufflevector(v, v, 2, 3); }
__device__ __forceinline__ v2f fma2(v2f a, v2f b, v2f c) {
    return __builtin_elementwise_fma(a, b, c);
}

template<int CTRL>
__device__ __forceinline__ float dpp_f(float x) {
    return __int_as_float(
        __builtin_amdgcn_update_dpp(0, __float_as_int(x), CTRL, 0xF, 0xF, true));
}
// sum across the 16 lanes of a DPP row (the e-group): 4 pure-VALU adds
__device__ __forceinline__ float row_sum16(float x) {
    x += dpp_f<0xB1>(x);    // quad_perm xor1
    x += dpp_f<0x4E>(x);    // quad_perm xor2
    x += dpp_f<0x124>(x);   // row_ror:4
    x += dpp_f<0x128>(x);   // row_ror:8
    return x;
}

// G row start for (o, ic): stride 20 rows + 8*o skew.
// store bank = (8o + 20ic + e) % 32: the 4 per-wave o-bases {0,8,16,24}
// tile the banks exactly 2-way (free). Consumer b128 base = (20ic+8j)%32,
// hf collides 2-way (free).
__device__ __forceinline__ int g_row(int o, int ic) {
    return (o * 8 + ic) * 20 + o * 8;
}

__global__ __launch_bounds__(256, 8)
void capsule_routing_kernel(const float* __restrict__ x,
                            const float* __restrict__ Wg,
                            float* __restrict__ out)
{
    __shared__ alignas(16) float pose_t[16 * 76];          // [a*4+b][k]  4864 B
    __shared__ alignas(16) float g_s[2676];                // G          10704 B
    __shared__ alignas(16) float coup_s[OUT_CAPS * 72];    // [o][k]      4608 B
    __shared__ float act_s[KKIN];                          //              288 B
    // total 20464 B -> 20480 rounded -> 8 blocks/CU (32 waves, HW max)

    const int tid = threadIdx.x;
    const int o = tid >> 4;        // out capsule
    const int e = tid & 15;        // atom = a*4+c
    const int c = e & 3;

    const int n   = blockIdx.x;
    const int b   = n / (HO * WO);
    const int rem = n - b * (HO * WO);
    const int ho  = rem / WO;
    const int wo  = rem - ho * WO;

    // ---- W row fragment from global (L1-cached, identical for all blocks):
    //      w01[ic] = (W[ic][o][c][0], W[ic][o][c][1]), w23 = ([2],[3]) ----
    v2f w01[IN_CAPS], w23[IN_CAPS];
    #pragma unroll
    for (int i = 0; i < IN_CAPS; ++i) {
        const v4f wv = *reinterpret_cast<const v4f*>(
            &Wg[((i * OUT_CAPS + o) * 4 + c) * 4]);
        w01[i] = lo2(wv);
        w23[i] = hi2(wv);
    }

    // ---- 3x3 patch: 9 px x 136 ch; pose stored transposed; coup r=0 init
    //      (softmax(0)*act = act/16) folded in ----
    for (int idx = tid; idx < KK * CIN; idx += 256) {
        int p  = idx / CIN;
        int cc = idx - p * CIN;
        int py = p / 3, px = p - py * 3;
        float val = x[(((b * H_IN + ho + py) * W_IN) + (wo + px)) * CIN + cc];
        int ic = cc / 17;
        int aa = cc - ic * 17;
        int k  = p * IN_CAPS + ic;
        if (aa == 16) {
            act_s[k] = val;
            const float cv = val * 0.0625f;
            #pragma unroll
            for (int j = 0; j < OUT_CAPS; ++j) coup_s[j * 72 + k] = cv;
        } else {
            pose_t[aa * 76 + k] = val;
        }
    }
    __syncthreads();

    // fused-phase ownership: thread pair (k = tid>>1, hf = tid&1) owns
    // logits[k][hf*8+j], j=0..7, accumulated in lreg8 across rounds.
    const int kf  = tid >> 1;
    const int hf  = tid & 1;
    const int ick = kf & 7;
    float lreg8[8] = {0.f,0.f,0.f,0.f,0.f,0.f,0.f,0.f};

    const v4f* cp = reinterpret_cast<const v4f*>(&coup_s[o * 72]);
    const v4f* pp = reinterpret_cast<const v4f*>(&pose_t[e * 76]);

    float v = 0.f;
    #pragma unroll 1
    for (int r = 0; r < 3; ++r) {
        // ---- phase B: M[ic] = sum_p coup[8p+ic][o] * pose_t[e][8p+ic]
        //      packed: M01=(ic0,ic1), M23=(ic2,ic3), M45, M67 ----
        v2f M01 = {0.f,0.f}, M23 = {0.f,0.f}, M45 = {0.f,0.f}, M67 = {0.f,0.f};
        #pragma unroll
        for (int p = 0; p < KK; ++p) {
            const v4f c0 = cp[2*p], c1 = cp[2*p+1];
            const v4f q0 = pp[2*p], q1 = pp[2*p+1];
            M01 = fma2(lo2(c0), lo2(q0), M01);
            M23 = fma2(hi2(c0), hi2(q0), M23);
            M45 = fma2(lo2(c1), lo2(q1), M45);
            M67 = fma2(hi2(c1), hi2(q1), M67);
        }
        const float Mc[8] = {M01.x, M01.y, M23.x, M23.y,
                             M45.x, M45.y, M67.x, M67.y};
        // U[j] = sum_ic W[ic,o,c,j] * M[ic]   (16 pk_fma)
        v2f U01 = {0.f,0.f}, U23 = {0.f,0.f};
        #pragma unroll
        for (int ic = 0; ic < 8; ++ic) {
            const v2f mm = {Mc[ic], Mc[ic]};
            U01 = fma2(w01[ic], mm, U01);
            U23 = fma2(w23[ic], mm, U23);
        }
        // quad allreduce: Z[j] = sum over quad lanes b of U_b[j] = s(a, c=j)
        float Z0 = U01.x, Z1 = U01.y, Z2 = U23.x, Z3 = U23.y;
        Z0 += dpp_f<0xB1>(Z0); Z1 += dpp_f<0xB1>(Z1);
        Z2 += dpp_f<0xB1>(Z2); Z3 += dpp_f<0xB1>(Z3);
        Z0 += dpp_f<0x4E>(Z0); Z1 += dpp_f<0x4E>(Z1);
        Z2 += dpp_f<0x4E>(Z2); Z3 += dpp_f<0x4E>(Z3);
        const float s = (c == 0) ? Z0 : (c == 1) ? Z1 : (c == 2) ? Z2 : Z3;

        // ---- phase C: squash ----
        const float sq = row_sum16(s * s);
        v = s * (sq / ((1.f + sq) * sqrtf(sq + 1e-7f)));

        if (r < 2) {
            // ---- G build from wreg2:
            //  G[ic,o,a,b=c] = sum_j W[ic,o,c,j]*v(o,a,j) ----
            const float vq0 = dpp_f<0x00>(v);
            const float vq1 = dpp_f<0x55>(v);
            const float vq2 = dpp_f<0xAA>(v);
            const float vq3 = dpp_f<0xFF>(v);
            const v2f vq01 = {vq0, vq1};
            const v2f vq23 = {vq2, vq3};
            #pragma unroll
            for (int ic = 0; ic < 8; ++ic) {
                v2f h = fma2(w23[ic], vq23, w01[ic] * vq01);
                g_s[g_row(o, ic) + e] = h.x + h.y;
            }
            __syncthreads();
            // ---- FUSED phase D part2 + phase A (144 threads, 2 per k) ----
            if (tid < 2 * KKIN) {
                // pose row kf from pose_t columns: 16 scalar b32,
                // banks (12j+kf)%32, hf-broadcast -> conflict-free
                float q[16];
                #pragma unroll
                for (int j = 0; j < 16; ++j) q[j] = pose_t[j * 76 + kf];
                const v2f q0 = {q[0],  q[1]},  q1 = {q[2],  q[3]};
                const v2f q2 = {q[4],  q[5]},  q3 = {q[6],  q[7]};
                const v2f q4 = {q[8],  q[9]},  q5 = {q[10], q[11]};
                const v2f q6 = {q[12], q[13]}, q7 = {q[14], q[15]};
                float lg[8];
                #pragma unroll
                for (int j = 0; j < 8; ++j) {
                    const int oo = hf * 8 + j;
                    const v4f* gp = reinterpret_cast<const v4f*>(
                        &g_s[g_row(oo, ick)]);
                    const v4f g0 = gp[0], g1 = gp[1], g2 = gp[2], g3 = gp[3];
                    v2f A = fma2(q2, lo2(g1), fma2(q4, lo2(g2),
                              fma2(q6, lo2(g3), q0 * lo2(g0))));
                    v2f Bv = fma2(q3, hi2(g1), fma2(q5, hi2(g2),
                              fma2(q7, hi2(g3), q1 * hi2(g0))));
                    lreg8[j] += (A.x + A.y) + (Bv.x + Bv.y);
                    lg[j] = lreg8[j];
                }
                // softmax over 16 o: 8 local + pair combine via DPP xor1
                float mx = -1e30f;
                #pragma unroll
                for (int j = 0; j < 8; ++j) mx = fmaxf(mx, lg[j]);
                mx = fmaxf(mx, dpp_f<0xB1>(mx));
                float sum = 0.f;
                #pragma unroll
                for (int j = 0; j < 8; ++j) { lg[j] = __expf(lg[j] - mx); sum += lg[j]; }
                sum += dpp_f<0xB1>(sum);
                const float scale = act_s[kf] / sum;
                #pragma unroll
                for (int j = 0; j < 8; ++j)
                    coup_s[(hf * 8 + j) * 72 + kf] = lg[j] * scale;
            }
            __syncthreads();
        }
    }

    // ---- out[n][o][e], coalesced ----
    out[n * 256 + tid] = v;
}

extern "C" void kernel_launch(void* const* d_in, const int* in_sizes, int n_in,
                              void* d_out, int out_size, void* d_ws, size_t ws_size,
                              hipStream_t stream) {
    const float* x  = (const float*)d_in[0];   // [2,48,48,136] fp32
    const float* Wt = (const float*)d_in[1];   // [8,16,4,4]    fp32
    float* outp = (float*)d_out;               // [2,46,46,16,16] fp32
    capsule_routing_kernel<<<dim3(NPIX), dim3(256), 0, stream>>>(x, Wt, outp);
}

// Round 3
// 98.913 us; speedup vs baseline: 1.5026x; 1.5026x over previous
//
#include <hip/hip_runtime.h>

// ConvCapsuleLayer: B=2, 48x48, IN_CAPS=8, ATOMS=16, KER=3, OUT_CAPS=16, R=3.
// One 256-thread block per pixel (N=4232). Thread t=(o=t>>4, a=(t>>2)&3, c=t&3).
// Round-14 == round-13 resubmitted verbatim (round-13 bench failed on
// container acquisition; kernel never measured).
// Round-13: round-12's LDS diet (20.46KB -> 8 blocks/CU HW cap) WITHOUT the
// register-poisoning hint. Round-12's __launch_bounds__(256,8) made the
// allocator crush 52->32 VGPR and spill (WRITE_SIZE 4.2MB->215MB, 2x slower).
// The 2nd arg is only a compiler budget; runtime occupancy = min(LDS,VGPR)
// caps. With (256,4) the code fits in ~52 VGPR (<=64), so runtime residency
// reaches 8 blocks/CU anyway via the LDS cut:
//  - pose_s dropped (5.8KB): fused phase reads pose rows from pose_t via 16
//    scalar b32 (banks (12j+kf)%32, hf-broadcast -> conflict-free).
//  - coup_s stride 72 (reads: bases (8o+8p)%32 distinct per-o, free;
//    writes: hf 2-way, free).
//  - g_s skew o*8: producer stores exactly 2-way; consumer b128 2-way.
//  - r=0 coupling init folded into the load loop (-1 barrier).

#define IN_CAPS 8
#define OUT_CAPS 16
#define KK 9
#define KKIN 72
#define BATCH 2
#define H_IN 48
#define W_IN 48
#define HO 46
#define WO 46
#define CIN 136
#define NPIX (BATCH*HO*WO)   // 4232

typedef float v2f __attribute__((ext_vector_type(2)));
typedef float v4f __attribute__((ext_vector_type(4)));

__device__ __forceinline__ v2f lo2(v4f v) { return __builtin_shufflevector(v, v, 0, 1); }
__device__ __forceinline__ v2f hi2(v4f v) { return __builtin_shufflevector(v, v, 2, 3); }
__device__ __forceinline__ v2f fma2(v2f a, v2f b, v2f c) {
    return __builtin_elementwise_fma(a, b, c);
}

template<int CTRL>
__device__ __forceinline__ float dpp_f(float x) {
    return __int_as_float(
        __builtin_amdgcn_update_dpp(0, __float_as_int(x), CTRL, 0xF, 0xF, true));
}
// sum across the 16 lanes of a DPP row (the e-group): 4 pure-VALU adds
__device__ __forceinline__ float row_sum16(float x) {
    x += dpp_f<0xB1>(x);    // quad_perm xor1
    x += dpp_f<0x4E>(x);    // quad_perm xor2
    x += dpp_f<0x124>(x);   // row_ror:4
    x += dpp_f<0x128>(x);   // row_ror:8
    return x;
}

// G row start for (o, ic): stride 20 rows + 8*o skew.
// store bank = (8o + 20ic + e) % 32: the 4 per-wave o-bases {0,8,16,24}
// tile the banks exactly 2-way (free). Consumer b128 base = (20ic+8j)%32,
// hf collides 2-way (free).
__device__ __forceinline__ int g_row(int o, int ic) {
    return (o * 8 + ic) * 20 + o * 8;
}

__global__ __launch_bounds__(256, 4)
void capsule_routing_kernel(const float* __restrict__ x,
                            const float* __restrict__ Wg,
                            float* __restrict__ out)
{
    __shared__ alignas(16) float pose_t[16 * 76];          // [a*4+b][k]  4864 B
    __shared__ alignas(16) float g_s[2676];                // G          10704 B
    __shared__ alignas(16) float coup_s[OUT_CAPS * 72];    // [o][k]      4608 B
    __shared__ float act_s[KKIN];                          //              288 B
    // total 20464 B -> 20480 rounded -> 8 blocks/CU (32 waves, HW max)

    const int tid = threadIdx.x;
    const int o = tid >> 4;        // out capsule
    const int e = tid & 15;        // atom = a*4+c
    const int c = e & 3;

    const int n   = blockIdx.x;
    const int b   = n / (HO * WO);
    const int rem = n - b * (HO * WO);
    const int ho  = rem / WO;
    const int wo  = rem - ho * WO;

    // ---- W row fragment from global (L1-cached, identical for all blocks):
    //      w01[ic] = (W[ic][o][c][0], W[ic][o][c][1]), w23 = ([2],[3]) ----
    v2f w01[IN_CAPS], w23[IN_CAPS];
    #pragma unroll
    for (int i = 0; i < IN_CAPS; ++i) {
        const v4f wv = *reinterpret_cast<const v4f*>(
            &Wg[((i * OUT_CAPS + o) * 4 + c) * 4]);
        w01[i] = lo2(wv);
        w23[i] = hi2(wv);
    }

    // ---- 3x3 patch: 9 px x 136 ch; pose stored transposed; coup r=0 init
    //      (softmax(0)*act = act/16) folded in ----
    for (int idx = tid; idx < KK * CIN; idx += 256) {
        int p  = idx / CIN;
        int cc = idx - p * CIN;
        int py = p / 3, px = p - py * 3;
        float val = x[(((b * H_IN + ho + py) * W_IN) + (wo + px)) * CIN + cc];
        int ic = cc / 17;
        int aa = cc - ic * 17;
        int k  = p * IN_CAPS + ic;
        if (aa == 16) {
            act_s[k] = val;
            const float cv = val * 0.0625f;
            #pragma unroll
            for (int j = 0; j < OUT_CAPS; ++j) coup_s[j * 72 + k] = cv;
        } else {
            pose_t[aa * 76 + k] = val;
        }
    }
    __syncthreads();

    // fused-phase ownership: thread pair (k = tid>>1, hf = tid&1) owns
    // logits[k][hf*8+j], j=0..7, accumulated in lreg8 across rounds.
    const int kf  = tid >> 1;
    const int hf  = tid & 1;
    const int ick = kf & 7;
    float lreg8[8] = {0.f,0.f,0.f,0.f,0.f,0.f,0.f,0.f};

    const v4f* cp = reinterpret_cast<const v4f*>(&coup_s[o * 72]);
    const v4f* pp = reinterpret_cast<const v4f*>(&pose_t[e * 76]);

    float v = 0.f;
    #pragma unroll 1
    for (int r = 0; r < 3; ++r) {
        // ---- phase B: M[ic] = sum_p coup[8p+ic][o] * pose_t[e][8p+ic]
        //      packed: M01=(ic0,ic1), M23=(ic2,ic3), M45, M67 ----
        v2f M01 = {0.f,0.f}, M23 = {0.f,0.f}, M45 = {0.f,0.f}, M67 = {0.f,0.f};
        #pragma unroll
        for (int p = 0; p < KK; ++p) {
            const v4f c0 = cp[2*p], c1 = cp[2*p+1];
            const v4f q0 = pp[2*p], q1 = pp[2*p+1];
            M01 = fma2(lo2(c0), lo2(q0), M01);
            M23 = fma2(hi2(c0), hi2(q0), M23);
            M45 = fma2(lo2(c1), lo2(q1), M45);
            M67 = fma2(hi2(c1), hi2(q1), M67);
        }
        const float Mc[8] = {M01.x, M01.y, M23.x, M23.y,
                             M45.x, M45.y, M67.x, M67.y};
        // U[j] = sum_ic W[ic,o,c,j] * M[ic]   (16 pk_fma)
        v2f U01 = {0.f,0.f}, U23 = {0.f,0.f};
        #pragma unroll
        for (int ic = 0; ic < 8; ++ic) {
            const v2f mm = {Mc[ic], Mc[ic]};
            U01 = fma2(w01[ic], mm, U01);
            U23 = fma2(w23[ic], mm, U23);
        }
        // quad allreduce: Z[j] = sum over quad lanes b of U_b[j] = s(a, c=j)
        float Z0 = U01.x, Z1 = U01.y, Z2 = U23.x, Z3 = U23.y;
        Z0 += dpp_f<0xB1>(Z0); Z1 += dpp_f<0xB1>(Z1);
        Z2 += dpp_f<0xB1>(Z2); Z3 += dpp_f<0xB1>(Z3);
        Z0 += dpp_f<0x4E>(Z0); Z1 += dpp_f<0x4E>(Z1);
        Z2 += dpp_f<0x4E>(Z2); Z3 += dpp_f<0x4E>(Z3);
        const float s = (c == 0) ? Z0 : (c == 1) ? Z1 : (c == 2) ? Z2 : Z3;

        // ---- phase C: squash ----
        const float sq = row_sum16(s * s);
        v = s * (sq / ((1.f + sq) * sqrtf(sq + 1e-7f)));

        if (r < 2) {
            // ---- G build from wreg2:
            //  G[ic,o,a,b=c] = sum_j W[ic,o,c,j]*v(o,a,j) ----
            const float vq0 = dpp_f<0x00>(v);
            const float vq1 = dpp_f<0x55>(v);
            const float vq2 = dpp_f<0xAA>(v);
            const float vq3 = dpp_f<0xFF>(v);
            const v2f vq01 = {vq0, vq1};
            const v2f vq23 = {vq2, vq3};
            #pragma unroll
            for (int ic = 0; ic < 8; ++ic) {
                v2f h = fma2(w23[ic], vq23, w01[ic] * vq01);
                g_s[g_row(o, ic) + e] = h.x + h.y;
            }
            __syncthreads();
            // ---- FUSED phase D part2 + phase A (144 threads, 2 per k) ----
            if (tid < 2 * KKIN) {
                // pose row kf from pose_t columns: 16 scalar b32,
                // banks (12j+kf)%32, hf-broadcast -> conflict-free
                float q[16];
                #pragma unroll
                for (int j = 0; j < 16; ++j) q[j] = pose_t[j * 76 + kf];
                const v2f q0 = {q[0],  q[1]},  q1 = {q[2],  q[3]};
                const v2f q2 = {q[4],  q[5]},  q3 = {q[6],  q[7]};
                const v2f q4 = {q[8],  q[9]},  q5 = {q[10], q[11]};
                const v2f q6 = {q[12], q[13]}, q7 = {q[14], q[15]};
                float lg[8];
                #pragma unroll
                for (int j = 0; j < 8; ++j) {
                    const int oo = hf * 8 + j;
                    const v4f* gp = reinterpret_cast<const v4f*>(
                        &g_s[g_row(oo, ick)]);
                    const v4f g0 = gp[0], g1 = gp[1], g2 = gp[2], g3 = gp[3];
                    v2f A = fma2(q2, lo2(g1), fma2(q4, lo2(g2),
                              fma2(q6, lo2(g3), q0 * lo2(g0))));
                    v2f Bv = fma2(q3, hi2(g1), fma2(q5, hi2(g2),
                              fma2(q7, hi2(g3), q1 * hi2(g0))));
                    lreg8[j] += (A.x + A.y) + (Bv.x + Bv.y);
                    lg[j] = lreg8[j];
                }
                // softmax over 16 o: 8 local + pair combine via DPP xor1
                float mx = -1e30f;
                #pragma unroll
                for (int j = 0; j < 8; ++j) mx = fmaxf(mx, lg[j]);
                mx = fmaxf(mx, dpp_f<0xB1>(mx));
                float sum = 0.f;
                #pragma unroll
                for (int j = 0; j < 8; ++j) { lg[j] = __expf(lg[j] - mx); sum += lg[j]; }
                sum += dpp_f<0xB1>(sum);
                const float scale = act_s[kf] / sum;
                #pragma unroll
                for (int j = 0; j < 8; ++j)
                    coup_s[(hf * 8 + j) * 72 + kf] = lg[j] * scale;
            }
            __syncthreads();
        }
    }

    // ---- out[n][o][e], coalesced ----
    out[n * 256 + tid] = v;
}

extern "C" void kernel_launch(void* const* d_in, const int* in_sizes, int n_in,
                              void* d_out, int out_size, void* d_ws, size_t ws_size,
                              hipStream_t stream) {
    const float* x  = (const float*)d_in[0];   // [2,48,48,136] fp32
    const float* Wt = (const float*)d_in[1];   // [8,16,4,4]    fp32
    float* outp = (float*)d_out;               // [2,46,46,16,16] fp32
    capsule_routing_kernel<<<dim3(NPIX), dim3(256), 0, stream>>>(x, Wt, outp);
}

// Round 4
// 89.892 us; speedup vs baseline: 1.6533x; 1.1003x over previous
//
#include <hip/hip_runtime.h>

// ConvCapsuleLayer: B=2, 48x48, IN_CAPS=8, ATOMS=16, KER=3, OUT_CAPS=16, R=3.
// One 256-thread block per pixel (N=4232). Thread t=(o=t>>4, a=(t>>2)&3, c=t&3).
// Round-15: revert to the measured-best round-11 layout (pose_s + pose_t,
// stride-76 coup, o*4 G skew, 26.6KB LDS — the 20.4KB diet regressed 16%:
// occupancy never moved, so residency was never the limiter). Then attack the
// per-block critical path:
//  - r=0 specialization: softmax(0)=1/16 => coup[k][o]=act[k]/16 is
//    o-independent. r0 phase B uses act directly (broadcast reads); the
//    coup-init phase AND its barrier are deleted (6 -> 5 barriers), plus
//    1152 LDS init stores out of the load phase tail.
//  - XCD-aware swizzle: 4232 = 8*529, pix=(bx&7)*529+(bx>>3) is bijective;
//    each XCD gets a contiguous ~529-pixel slab (~350KB x-data -> L2-resident).
//    FETCH 8.3MB (3.6x overfetch) -> ~2-3MB, load-phase miss latency down.

#define IN_CAPS 8
#define OUT_CAPS 16
#define KK 9
#define KKIN 72
#define BATCH 2
#define H_IN 48
#define W_IN 48
#define HO 46
#define WO 46
#define CIN 136
#define NPIX (BATCH*HO*WO)   // 4232 = 8*529

typedef float v2f __attribute__((ext_vector_type(2)));
typedef float v4f __attribute__((ext_vector_type(4)));

__device__ __forceinline__ v2f lo2(v4f v) { return __builtin_shufflevector(v, v, 0, 1); }
__device__ __forceinline__ v2f hi2(v4f v) { return __builtin_shufflevector(v, v, 2, 3); }
__device__ __forceinline__ v2f fma2(v2f a, v2f b, v2f c) {
    return __builtin_elementwise_fma(a, b, c);
}

template<int CTRL>
__device__ __forceinline__ float dpp_f(float x) {
    return __int_as_float(
        __builtin_amdgcn_update_dpp(0, __float_as_int(x), CTRL, 0xF, 0xF, true));
}
// sum across the 16 lanes of a DPP row (the e-group): 4 pure-VALU adds
__device__ __forceinline__ float row_sum16(float x) {
    x += dpp_f<0xB1>(x);    // quad_perm xor1
    x += dpp_f<0x4E>(x);    // quad_perm xor2
    x += dpp_f<0x124>(x);   // row_ror:4
    x += dpp_f<0x128>(x);   // row_ror:8
    return x;
}

// pose_s row start: stride 20 + skew in {0,4} (round-11 verified layout)
__device__ __forceinline__ int pose_row(int k) {
    return k * 20 + ((k >> 3) & 1) * 4;
}
// G row start for (o, ic): stride 20 rows + 4*o skew (round-11 verified)
__device__ __forceinline__ int g_row(int o, int ic) {
    return (o * 8 + ic) * 20 + o * 4;
}

__global__ __launch_bounds__(256, 4)
void capsule_routing_kernel(const float* __restrict__ x,
                            const float* __restrict__ Wg,
                            float* __restrict__ out)
{
    __shared__ alignas(16) float pose_s[1440];             // skewed [k][atom] 5760 B
    __shared__ alignas(16) float pose_t[16 * 76];          // [a*4+b][k]      4864 B
    __shared__ alignas(16) float act_s[KKIN];              //                  288 B
    __shared__ alignas(16) float g_s[2620];                // G              10480 B
    __shared__ alignas(16) float coup_s[OUT_CAPS * 76];    // [o][k]          4864 B
    // total ~26.3 KB -> 6 blocks/CU (round-11 proven)

    const int tid = threadIdx.x;
    const int o = tid >> 4;        // out capsule
    const int e = tid & 15;        // atom = a*4+c
    const int c = e & 3;

    // XCD-aware bijective swizzle: consecutive blocks round-robin XCDs;
    // give XCD (bx&7) the contiguous pixel slab [ (bx&7)*529, +529 ).
    const int bx = blockIdx.x;
    const int n  = (bx & 7) * (NPIX / 8) + (bx >> 3);

    const int b   = n / (HO * WO);
    const int rem = n - b * (HO * WO);
    const int ho  = rem / WO;
    const int wo  = rem - ho * WO;

    // ---- W row fragment from global (L1-cached, identical for all blocks):
    //      w01[ic] = (W[ic][o][c][0], W[ic][o][c][1]), w23 = ([2],[3]) ----
    v2f w01[IN_CAPS], w23[IN_CAPS];
    #pragma unroll
    for (int i = 0; i < IN_CAPS; ++i) {
        const v4f wv = *reinterpret_cast<const v4f*>(
            &Wg[((i * OUT_CAPS + o) * 4 + c) * 4]);
        w01[i] = lo2(wv);
        w23[i] = hi2(wv);
    }

    // ---- 3x3 patch: 9 px x 136 ch; pose stored in BOTH layouts; no coup
    //      init needed (r0 coupling handled algebraically) ----
    for (int idx = tid; idx < KK * CIN; idx += 256) {
        int p  = idx / CIN;
        int cc = idx - p * CIN;
        int py = p / 3, px = p - py * 3;
        float val = x[(((b * H_IN + ho + py) * W_IN) + (wo + px)) * CIN + cc];
        int ic = cc / 17;
        int aa = cc - ic * 17;
        int k  = p * IN_CAPS + ic;
        if (aa == 16) {
            act_s[k] = val;
        } else {
            pose_s[pose_row(k) + aa] = val;
            pose_t[aa * 76 + k] = val;
        }
    }
    __syncthreads();

    // fused-phase ownership: thread pair (k = tid>>1, hf = tid&1) owns
    // logits[k][hf*8+j], j=0..7, accumulated in lreg8 across rounds.
    const int kf  = tid >> 1;
    const int hf  = tid & 1;
    const int ick = kf & 7;
    float lreg8[8] = {0.f,0.f,0.f,0.f,0.f,0.f,0.f,0.f};

    const v4f* cp = reinterpret_cast<const v4f*>(&coup_s[o * 76]);
    const v4f* pp = reinterpret_cast<const v4f*>(&pose_t[e * 76]);
    const v4f* ap = reinterpret_cast<const v4f*>(act_s);

    float v = 0.f;

    // U[j] from M fragments + quad allreduce + squash -> this thread's v
    auto finishBU = [&](v2f M01, v2f M23, v2f M45, v2f M67, float mscale) {
        const float Mc[8] = {M01.x, M01.y, M23.x, M23.y,
                             M45.x, M45.y, M67.x, M67.y};
        v2f U01 = {0.f,0.f}, U23 = {0.f,0.f};
        #pragma unroll
        for (int ic = 0; ic < 8; ++ic) {
            const v2f mm = {Mc[ic], Mc[ic]};
            U01 = fma2(w01[ic], mm, U01);
            U23 = fma2(w23[ic], mm, U23);
        }
        const v2f sc = {mscale, mscale};
        U01 *= sc; U23 *= sc;
        // quad allreduce: Z[j] = s(a, c=j)
        float Z0 = U01.x, Z1 = U01.y, Z2 = U23.x, Z3 = U23.y;
        Z0 += dpp_f<0xB1>(Z0); Z1 += dpp_f<0xB1>(Z1);
        Z2 += dpp_f<0xB1>(Z2); Z3 += dpp_f<0xB1>(Z3);
        Z0 += dpp_f<0x4E>(Z0); Z1 += dpp_f<0x4E>(Z1);
        Z2 += dpp_f<0x4E>(Z2); Z3 += dpp_f<0x4E>(Z3);
        const float s = (c == 0) ? Z0 : (c == 1) ? Z1 : (c == 2) ? Z2 : Z3;
        // squash
        const float sq = row_sum16(s * s);
        v = s * (sq / ((1.f + sq) * sqrtf(sq + 1e-7f)));
    };

    // G build + fused logit-update/softmax -> writes coup_s for next round
    auto g_fused = [&]() {
        const float vq0 = dpp_f<0x00>(v);
        const float vq1 = dpp_f<0x55>(v);
        const float vq2 = dpp_f<0xAA>(v);
        const float vq3 = dpp_f<0xFF>(v);
        const v2f vq01 = {vq0, vq1};
        const v2f vq23 = {vq2, vq3};
        #pragma unroll
        for (int ic = 0; ic < 8; ++ic) {
            v2f h = fma2(w23[ic], vq23, w01[ic] * vq01);
            g_s[g_row(o, ic) + e] = h.x + h.y;
        }
        __syncthreads();
        if (tid < 2 * KKIN) {
            const v4f* pk = reinterpret_cast<const v4f*>(
                &pose_s[pose_row(kf)]);
            const v4f p0 = pk[0], p1 = pk[1], p2 = pk[2], p3 = pk[3];
            const v2f q0 = lo2(p0), q1 = hi2(p0), q2 = lo2(p1), q3 = hi2(p1);
            const v2f q4 = lo2(p2), q5 = hi2(p2), q6 = lo2(p3), q7 = hi2(p3);
            float lg[8];
            #pragma unroll
            for (int j = 0; j < 8; ++j) {
                const int oo = hf * 8 + j;
                const v4f* gp = reinterpret_cast<const v4f*>(
                    &g_s[g_row(oo, ick)]);
                const v4f g0 = gp[0], g1 = gp[1], g2 = gp[2], g3 = gp[3];
                v2f A = fma2(q2, lo2(g1), fma2(q4, lo2(g2),
                          fma2(q6, lo2(g3), q0 * lo2(g0))));
                v2f Bv = fma2(q3, hi2(g1), fma2(q5, hi2(g2),
                          fma2(q7, hi2(g3), q1 * hi2(g0))));
                lreg8[j] += (A.x + A.y) + (Bv.x + Bv.y);
                lg[j] = lreg8[j];
            }
            // softmax over 16 o: 8 local + pair combine via DPP xor1
            float mx = -1e30f;
            #pragma unroll
            for (int j = 0; j < 8; ++j) mx = fmaxf(mx, lg[j]);
            mx = fmaxf(mx, dpp_f<0xB1>(mx));
            float sum = 0.f;
            #pragma unroll
            for (int j = 0; j < 8; ++j) { lg[j] = __expf(lg[j] - mx); sum += lg[j]; }
            sum += dpp_f<0xB1>(sum);
            const float scale = act_s[kf] / sum;
            #pragma unroll
            for (int j = 0; j < 8; ++j)
                coup_s[(hf * 8 + j) * 76 + kf] = lg[j] * scale;
        }
        __syncthreads();
    };

    // ================= r = 0 (coup = act/16, o-independent) =================
    {
        v2f M01 = {0.f,0.f}, M23 = {0.f,0.f}, M45 = {0.f,0.f}, M67 = {0.f,0.f};
        #pragma unroll
        for (int p = 0; p < KK; ++p) {
            const v4f a0 = ap[2*p], a1 = ap[2*p+1];   // act[8p..8p+7], broadcast
            const v4f q0 = pp[2*p], q1 = pp[2*p+1];
            M01 = fma2(lo2(a0), lo2(q0), M01);
            M23 = fma2(hi2(a0), hi2(q0), M23);
            M45 = fma2(lo2(a1), lo2(q1), M45);
            M67 = fma2(hi2(a1), hi2(q1), M67);
        }
        finishBU(M01, M23, M45, M67, 0.0625f);   // fold 1/16 coupling here
        g_fused();
    }

    // ================= r = 1 =================
    {
        v2f M01 = {0.f,0.f}, M23 = {0.f,0.f}, M45 = {0.f,0.f}, M67 = {0.f,0.f};
        #pragma unroll
        for (int p = 0; p < KK; ++p) {
            const v4f c0 = cp[2*p], c1 = cp[2*p+1];
            const v4f q0 = pp[2*p], q1 = pp[2*p+1];
            M01 = fma2(lo2(c0), lo2(q0), M01);
            M23 = fma2(hi2(c0), hi2(q0), M23);
            M45 = fma2(lo2(c1), lo2(q1), M45);
            M67 = fma2(hi2(c1), hi2(q1), M67);
        }
        finishBU(M01, M23, M45, M67, 1.0f);
        g_fused();
    }

    // ================= r = 2 (no update afterwards) =================
    {
        v2f M01 = {0.f,0.f}, M23 = {0.f,0.f}, M45 = {0.f,0.f}, M67 = {0.f,0.f};
        #pragma unroll
        for (int p = 0; p < KK; ++p) {
            const v4f c0 = cp[2*p], c1 = cp[2*p+1];
            const v4f q0 = pp[2*p], q1 = pp[2*p+1];
            M01 = fma2(lo2(c0), lo2(q0), M01);
            M23 = fma2(hi2(c0), hi2(q0), M23);
            M45 = fma2(lo2(c1), lo2(q1), M45);
            M67 = fma2(hi2(c1), hi2(q1), M67);
        }
        finishBU(M01, M23, M45, M67, 1.0f);
    }

    // ---- out[n][o][e], coalesced (n = swizzled pixel id) ----
    out[n * 256 + tid] = v;
}

extern "C" void kernel_launch(void* const* d_in, const int* in_sizes, int n_in,
                              void* d_out, int out_size, void* d_ws, size_t ws_size,
                              hipStream_t stream) {
    const float* x  = (const float*)d_in[0];   // [2,48,48,136] fp32
    const float* Wt = (const float*)d_in[1];   // [8,16,4,4]    fp32
    float* outp = (float*)d_out;               // [2,46,46,16,16] fp32
    capsule_routing_kernel<<<dim3(NPIX), dim3(256), 0, stream>>>(x, Wt, outp);
}